// Round 16
// baseline (72.981 us; speedup 1.0000x reference)
//
#include <hip/hip_runtime.h>
#include <stdint.h>

#define NROW 1024
#define DCOL 8192
#define T1   1024
#define EPT  8
#define TSZ  1024    // CDF table entries (top 10 bits of sortable key)
#define NBIN 16384   // logical bins (u16-packed, 2 per u32 word)
#define NHW  8193    // histogram words (8192 + sentinel)

typedef unsigned long long u64;

// ---------- compile-time monotone N(0,1)-CDF binning table (scale 16384) ----
struct CdfTbl { uint32_t e[TSZ]; };

constexpr double cpow2(int p){
  double r = 1.0;
  if (p >= 0){ for (int i=0;i<p;i++) r *= 2.0; }
  else       { for (int i=0;i<-p;i++) r *= 0.5; }
  return r;
}
constexpr double key_to_x(uint32_t k){
  uint32_t u = (k & 0x80000000u) ? (k ^ 0x80000000u) : ~k;
  double sign = (u >> 31) ? -1.0 : 1.0;
  int E = (int)((u >> 23) & 255u);
  double M = (double)(u & 0x7FFFFFu);
  double mag = 0.0;
  if (E == 255)      mag = 1.0e10;              // inf/NaN band -> clamped below
  else if (E == 0)   mag = M * cpow2(-149);
  else               mag = (1.0 + M / 8388608.0) * cpow2(E - 127);
  return sign * mag;
}
constexpr double cerf(double z){                 // series, |z| <= ~3 (clamped)
  double term = z, sum = z;
  for (int n=1; n<60; ++n){
    term *= -z*z / (double)n;
    sum  += term / (double)(2*n+1);
  }
  return sum * 1.1283791670955126;               // 2/sqrt(pi)
}
constexpr double cphi(double x){
  if (x >  4.0) return 1.0;
  if (x < -4.0) return 0.0;
  return 0.5 + 0.5 * cerf(x * 0.7071067811865476);
}
constexpr CdfTbl make_tbl(){
  CdfTbl T{};
  uint32_t b[TSZ+1] = {};
  uint32_t prev = 0;
  for (int t=0; t<=TSZ; ++t){
    uint32_t bt;
    if (t == TSZ) bt = (uint32_t)NBIN;
    else {
      double c = cphi(key_to_x((uint32_t)t << 22));
      long v = (long)(c * (double)NBIN);
      if (v < 0) v = 0;
      if (v > NBIN-1) v = NBIN-1;
      bt = (uint32_t)v;
    }
    if (bt < prev) bt = prev;                    // enforce monotone
    prev = bt;
    b[t] = bt;
  }
  for (int t=0; t<TSZ; ++t) T.e[t] = (b[t] << 16) | (b[t+1] - b[t]);
  return T;
}
__device__ const CdfTbl d_cdf = make_tbl();

// order-preserving float -> uint32 transform
__device__ __forceinline__ uint32_t sortable_key(float f){
  uint32_t u = __float_as_uint(f);
  return u ^ ((uint32_t)((int32_t)u >> 31) | 0x80000000u);
}

// ---------- DPP cross-lane scans (zero-LDS) ----------
__device__ __forceinline__ uint32_t wave_scan_add(uint32_t v){
  int x = (int)v, tmp;
  tmp = __builtin_amdgcn_update_dpp(0, x, 0x111, 0xf, 0xf, false); x += tmp;
  tmp = __builtin_amdgcn_update_dpp(0, x, 0x112, 0xf, 0xf, false); x += tmp;
  tmp = __builtin_amdgcn_update_dpp(0, x, 0x114, 0xf, 0xf, false); x += tmp;
  tmp = __builtin_amdgcn_update_dpp(0, x, 0x118, 0xf, 0xf, false); x += tmp;
  tmp = __builtin_amdgcn_update_dpp(0, x, 0x142, 0xa, 0xf, false); x += tmp; // bcast15
  tmp = __builtin_amdgcn_update_dpp(0, x, 0x143, 0xc, 0xf, false); x += tmp; // bcast31
  return (uint32_t)x;
}
__device__ __forceinline__ uint32_t row16_scan_add(uint32_t v){
  int x = (int)v, tmp;
  tmp = __builtin_amdgcn_update_dpp(0, x, 0x111, 0xf, 0xf, false); x += tmp;
  tmp = __builtin_amdgcn_update_dpp(0, x, 0x112, 0xf, 0xf, false); x += tmp;
  tmp = __builtin_amdgcn_update_dpp(0, x, 0x114, 0xf, 0xf, false); x += tmp;
  tmp = __builtin_amdgcn_update_dpp(0, x, 0x118, 0xf, 0xf, false); x += tmp;
  return (uint32_t)x;
}

// One block ranks one row (r15 structure + doubleton fast path):
// singleton buckets (61% of keys): rank = st, no scatter, no reads.
// doubleton buckets (30%): partner at known slot st+(ord^1) -- one unclamped
// read, no loop. general loop serves only cnt>=3 (9%), so most 4-key groups
// skip it entirely. Multi-bucket exactness & tie handling unchanged.
extern "C" __global__ void __launch_bounds__(T1)
rank_kernel(const float* __restrict__ pred, const float* __restrict__ eeg,
            uint16_t* __restrict__ ranks,
            double* __restrict__ msepartA, double* __restrict__ msepartB)
{
  __shared__ uint32_t h[NHW];       // 32.8 KB: packed counts -> packed prefixes
  __shared__ uint32_t ek[DCOL];     // 32 KB: scattered keys (multi-buckets only)
  __shared__ uint32_t Tl[TSZ];      // 4 KB: CDF table; tie list after binning
  __shared__ uint32_t wt[16];
  __shared__ uint32_t listn;
  __shared__ double   redd[16];

  const int t = threadIdx.x, bid = blockIdx.x;
  const int pair = ((bid >> 4) << 3) | (bid & 7);   // [0,1024), twice each
  const bool is_eeg = (bid >> 3) & 1;
  const int lane = t & 63, wid = t >> 6;
  const float* src = is_eeg ? (eeg  + (size_t)pair * DCOL)
                            : (pred + (size_t)pair * DCOL);

  const float4* s4 = (const float4*)(src + t * EPT);
  float4 va = s4[0], vb = s4[1];

  // zero hist words (b128), load table slice, sentinel, tie counter
  {
    uint4 z = make_uint4(0u,0u,0u,0u);
    *(uint4*)&h[t*EPT]   = z;
    *(uint4*)&h[t*EPT+4] = z;
  }
  Tl[t] = d_cdf.e[t];
  if (t == 0){ listn = 0u; h[NHW-1] = (uint32_t)DCOL; } // pf16[16384] = 8192

  // balanced MSE: this block's half of the columns, against counterpart row
  double msum = 0.0;
  {
    const bool mse_act = is_eeg ? (t >= T1/2) : (t < T1/2);
    if (mse_act){
      const float* other = is_eeg ? (pred + (size_t)pair * DCOL)
                                  : (eeg  + (size_t)pair * DCOL);
      const float4* o4 = (const float4*)(other + t * EPT);
      float4 qa = o4[0], qb = o4[1];
      float d;
      d=qa.x-va.x; msum += (double)(d*d);
      d=qa.y-va.y; msum += (double)(d*d);
      d=qa.z-va.z; msum += (double)(d*d);
      d=qa.w-va.w; msum += (double)(d*d);
      d=qb.x-vb.x; msum += (double)(d*d);
      d=qb.y-vb.y; msum += (double)(d*d);
      d=qb.z-vb.z; msum += (double)(d*d);
      d=qb.w-vb.w; msum += (double)(d*d);
    }
  }

  uint32_t key[EPT];
  key[0]=sortable_key(va.x); key[1]=sortable_key(va.y);
  key[2]=sortable_key(va.z); key[3]=sortable_key(va.w);
  key[4]=sortable_key(vb.x); key[5]=sortable_key(vb.y);
  key[6]=sortable_key(vb.z); key[7]=sortable_key(vb.w);
  __syncthreads();                               // (1) zeros + table visible

  // ---- bin via table + packed histogram; atomic return = arrival order ----
  uint32_t bin[EPT], ord[EPT];
  #pragma unroll
  for (int j=0;j<EPT;j++){
    uint32_t tv = Tl[key[j] >> 22];
    bin[j] = (tv >> 16) + __umulhi(key[j] << 10, tv & 0xFFFFu);
  }
  #pragma unroll
  for (int j=0;j<EPT;j++){
    uint32_t sh = (bin[j] & 1u) << 4;
    uint32_t old = atomicAdd(&h[bin[j] >> 1], 1u << sh);
    ord[j] = (old >> sh) & 0xFFFFu;              // counts <= 8192: no carry
  }
  __syncthreads();                               // (2)

  // ---- scan: words become packed u16 exclusive prefixes, in place ----
  {
    uint4 ca = *(const uint4*)&h[t*EPT];
    uint4 cb = *(const uint4*)&h[t*EPT+4];
    uint32_t w[8] = {ca.x,ca.y,ca.z,ca.w,cb.x,cb.y,cb.z,cb.w};
    uint32_t tot = 0;
    #pragma unroll
    for (int k=0;k<8;k++) tot += (w[k] & 0xFFFFu) + (w[k] >> 16);
    uint32_t v = wave_scan_add(tot);             // inclusive, DPP (no LDS)
    if (lane==63) wt[wid]=v;
    __syncthreads();                             // (3)
    uint32_t y = wt[lane & 15];
    uint32_t pre = row16_scan_add(y);
    uint32_t off = wid ? (uint32_t)__builtin_amdgcn_readlane((int)pre, wid-1) : 0u;
    uint32_t run = off + v - tot;
    uint32_t o[8];
    #pragma unroll
    for (int k=0;k<8;k++){
      uint32_t p0 = run; run += (w[k] & 0xFFFFu);
      uint32_t p1 = run; run += (w[k] >> 16);
      o[k] = p0 | (p1 << 16);
    }
    *(uint4*)&h[t*EPT]   = make_uint4(o[0],o[1],o[2],o[3]);
    *(uint4*)&h[t*EPT+4] = make_uint4(o[4],o[5],o[6],o[7]);
  }
  __syncthreads();                               // (4)

  // ---- scatter (no atomics), MULTI-buckets only ----
  const uint16_t* pf = (const uint16_t*)h;
  uint32_t stj[EPT], cntj[EPT];
  #pragma unroll
  for (int j=0;j<EPT;j++){
    uint32_t st = pf[bin[j]];
    uint32_t en = pf[bin[j] + 1];                // sentinel covers bin 16383
    stj[j]  = st;
    cntj[j] = en - st;
    if (cntj[j] > 1u) ek[st + ord[j]] = key[j];
  }
  __syncthreads();                               // (5) scatter complete

  uint32_t rk[EPT];
  uint32_t tiedmask = 0u;

  // ---- doubleton fast path (cnt==2): partner at known slot, one read ----
  #pragma unroll
  for (int j=0;j<EPT;j++){
    if (cntj[j] == 2u){
      uint32_t partner = ek[stj[j] + (ord[j] ^ 1u)];
      rk[j] = stj[j] + ((partner < key[j]) ? 1u : 0u);
      if (partner == key[j]){                    // rare: true float dup
        uint32_t pp = atomicAdd(&listn, 1u);
        if (pp < TSZ/2){ Tl[2*pp] = key[j]; Tl[2*pp+1] = (uint32_t)(t*EPT+j); }
        tiedmask |= (1u << j);
      }
    } else if (cntj[j] == 1u){
      rk[j] = stj[j];                            // singleton: rank = start
    }
  }

  // ---- general path: ILP-grouped count, cnt>=3 lanes only (~9% of keys) ----
  #pragma unroll
  for (int grp=0; grp<2; ++grp){
    uint32_t less[4] = {0,0,0,0}, eqc[4] = {0,0,0,0};
    uint32_t mx = 0;
    #pragma unroll
    for (int q=0;q<4;q++){
      uint32_t c = cntj[grp*4+q];
      mx = max(mx, (c > 2u) ? c : 0u);           // groups w/o cnt>=3: skip
    }
    for (uint32_t p=0; p<mx; ++p){
      uint32_t k2[4];
      #pragma unroll
      for (int q=0;q<4;q++){                     // reads only for cnt>=3 lanes
        int j = grp*4+q;
        if (cntj[j] > 2u) k2[q] = ek[stj[j] + min(p, cntj[j]-1u)];
        else              k2[q] = 0u;
      }
      #pragma unroll
      for (int q=0;q<4;q++){
        int j = grp*4+q;
        if (cntj[j] > 2u && p < cntj[j]){
          less[q] += (k2[q] <  key[j]) ? 1u : 0u;
          eqc[q]  += (k2[q] == key[j]) ? 1u : 0u;
        }
      }
    }
    #pragma unroll
    for (int q=0;q<4;q++){
      int j = grp*4+q;
      if (cntj[j] > 2u){
        rk[j] = stj[j] + less[q];
        if (eqc[q] > 1u){                        // rare: true float dup
          uint32_t pp = atomicAdd(&listn, 1u);
          if (pp < TSZ/2){ Tl[2*pp] = key[j]; Tl[2*pp+1] = (uint32_t)(t*EPT+j); }
          tiedmask |= (1u << j);
        }
      }
    }
  }
  __syncthreads();                               // (6) tie list complete
  if (tiedmask){
    uint32_t n = min(listn, (uint32_t)(TSZ/2));
    #pragma unroll
    for (int j=0;j<EPT;j++){
      if (tiedmask & (1u<<j)){
        uint32_t add = 0, me = (uint32_t)(t*EPT+j);
        for (uint32_t q=0;q<n;q++)
          add += (Tl[2*q] == key[j] && Tl[2*q+1] < me) ? 1u : 0u;
        rk[j] += add;
      }
    }
  }

  uint4 pk;
  pk.x = rk[0] | (rk[1]<<16);
  pk.y = rk[2] | (rk[3]<<16);
  pk.z = rk[4] | (rk[5]<<16);
  pk.w = rk[6] | (rk[7]<<16);
  const size_t orow = is_eeg ? (size_t)(NROW + pair) : (size_t)pair;
  *(uint4*)(ranks + orow*DCOL + (size_t)t*EPT) = pk;

  // block-wide MSE-half reduction (inactive threads contribute 0)
  #pragma unroll
  for (int o=32;o>0;o>>=1) msum += __shfl_down(msum,o,64);
  if (lane==0) redd[wid]=msum;
  __syncthreads();
  if (t==0){
    double m=0.0;
    #pragma unroll
    for (int w=0;w<16;w++) m += redd[w];
    (is_eeg ? msepartB : msepartA)[pair] = m;
  }
}

// ---------- atomic-free back end (256 thr: 8 waves/CU for latency hiding) ---
extern "C" __global__ void __launch_bounds__(256)
colsum_part_kernel(const uint16_t* __restrict__ ranks,
                   u64* __restrict__ SABpart, u64* __restrict__ dotpart)
{
  __shared__ u64 redu[4];
  const int t = threadIdx.x;
  const int bx = blockIdx.x, by = blockIdx.y;
  const int col = bx*1024 + t*4;
  const int r0  = by*16;
  const uint16_t* rp = ranks;
  const uint16_t* re = ranks + (size_t)NROW*DCOL;
  uint32_t sa[4] = {0,0,0,0};
  uint32_t sb[4] = {0,0,0,0};
  u64 dt = 0ull;
  #pragma unroll
  for (int i=0;i<16;i++){
    uint2 a = *(const uint2*)&rp[(size_t)(r0+i)*DCOL + col];
    uint2 b = *(const uint2*)&re[(size_t)(r0+i)*DCOL + col];
    uint32_t aw[4] = {a.x&0xFFFFu,a.x>>16,a.y&0xFFFFu,a.y>>16};
    uint32_t bw[4] = {b.x&0xFFFFu,b.x>>16,b.y&0xFFFFu,b.y>>16};
    uint32_t rowdt = 0;
    #pragma unroll
    for (int k=0;k<4;k++){ sa[k]+=aw[k]; sb[k]+=bw[k]; rowdt += aw[k]*bw[k]; }
    dt += (u64)rowdt;                            // rowdt <= 4*8191^2 < 2^32
  }
  u64* dst = SABpart + (size_t)by*DCOL + col;
  #pragma unroll
  for (int k=0;k<4;k++) dst[k] = (u64)sa[k] | ((u64)sb[k]<<32);

  #pragma unroll
  for (int o=32;o>0;o>>=1) dt += __shfl_down(dt,o,64);
  int lane=t&63, wid=t>>6;
  if (lane==0) redu[wid]=dt;
  __syncthreads();
  if (t==0) dotpart[by*8+bx] = redu[0]+redu[1]+redu[2]+redu[3];
}

extern "C" __global__ void __launch_bounds__(128)
reduce2_kernel(const u64* __restrict__ SABpart, double* __restrict__ Spart)
{
  __shared__ double red[2];
  const int t = threadIdx.x;
  const int col = blockIdx.x*128 + t;
  u64 s = 0ull;
  #pragma unroll
  for (int by=0; by<64; by++) s += SABpart[(size_t)by*DCOL + col];
  const double NMU = 4193792.0;                  // N * mu, mu = (D-1)/2
  double d = ((double)(uint32_t)s - NMU) * ((double)(uint32_t)(s>>32) - NMU);
  #pragma unroll
  for (int o=32;o>0;o>>=1) d += __shfl_down(d,o,64);
  int lane=t&63, wid=t>>6;
  if (lane==0) red[wid]=d;
  __syncthreads();
  if (t==0) Spart[blockIdx.x] = red[0]+red[1];
}

extern "C" __global__ void __launch_bounds__(256)
final_kernel(const double* __restrict__ Spart, const u64* __restrict__ dotpart,
             const double* __restrict__ msepartA,
             const double* __restrict__ msepartB, float* __restrict__ out)
{
  __shared__ double wpartd[4], wpartm[4];
  __shared__ u64 wpartu[4];
  const int t = threadIdx.x;
  double s = (t < 64) ? Spart[t] : 0.0;
  u64 d = dotpart[t] + dotpart[t+256];
  double m = 0.0;
  for (int i=t;i<NROW;i+=256) m += msepartA[i] + msepartB[i];
  #pragma unroll
  for (int o=32;o>0;o>>=1){
    s+=__shfl_down(s,o,64); m+=__shfl_down(m,o,64); d+=__shfl_down(d,o,64);
  }
  int lane=t&63, wid=t>>6;
  if (lane==0){ wpartd[wid]=s; wpartm[wid]=m; wpartu[wid]=d; }
  __syncthreads();
  if (t==0){
    double sasb   = wpartd[0]+wpartd[1]+wpartd[2]+wpartd[3];
    double msesum = wpartm[0]+wpartm[1]+wpartm[2]+wpartm[3];
    double dot    = (double)(wpartu[0]+wpartu[1]+wpartu[2]+wpartu[3]);
    const double C     = 45812983808.0;          // D*(D^2-1)/12
    const double NDMU2 = 140703130714112.0;      // N * D * mu^2
    double diag_sum = (dot - NDMU2) / C;         // sum_i corr_ii
    double pos = diag_sum / (double)NROW;
    double stotal = sasb / C;                    // sum_ij corr_ij
    double neg = (stotal - diag_sum) / ((double)NROW*(double)(NROW-1));
    double loss1 = msesum / ((double)NROW*(double)DCOL);
    out[0] = (float)(loss1 + 1.0 - pos + neg);
  }
}

// ---------- atomic fallback (only if ws too small for partials) ----------
extern "C" __global__ void __launch_bounds__(256)
colsum_atomic_kernel(const uint16_t* __restrict__ ranks,
                     u64* __restrict__ SAB, u64* __restrict__ dotacc)
{
  const int t = threadIdx.x;
  const int col = blockIdx.x*2048 + t*8;
  const int r0  = blockIdx.y*16;
  const uint16_t* rp = ranks;
  const uint16_t* re = ranks + (size_t)NROW*DCOL;
  uint32_t sa[8] = {0,0,0,0,0,0,0,0};
  uint32_t sb[8] = {0,0,0,0,0,0,0,0};
  u64 dt = 0ull;
  for (int i=0;i<16;i++){
    uint4 a = *(const uint4*)&rp[(size_t)(r0+i)*DCOL + col];
    uint4 b = *(const uint4*)&re[(size_t)(r0+i)*DCOL + col];
    uint32_t aw[8] = {a.x&0xFFFFu,a.x>>16,a.y&0xFFFFu,a.y>>16,
                      a.z&0xFFFFu,a.z>>16,a.w&0xFFFFu,a.w>>16};
    uint32_t bw[8] = {b.x&0xFFFFu,b.x>>16,b.y&0xFFFFu,b.y>>16,
                      b.z&0xFFFFu,b.z>>16,b.w&0xFFFFu,b.w>>16};
    uint32_t rowdt = 0;
    #pragma unroll
    for (int k=0;k<8;k++){ sa[k]+=aw[k]; sb[k]+=bw[k]; rowdt += aw[k]*bw[k]; }
    dt += (u64)rowdt;
  }
  #pragma unroll
  for (int k=0;k<8;k++)
    atomicAdd(&SAB[col+k], (u64)sa[k] | ((u64)sb[k]<<32));
  #pragma unroll
  for (int o=32;o>0;o>>=1) dt += __shfl_down(dt,o,64);
  if ((t&63)==0) atomicAdd(dotacc, dt);
}

extern "C" __global__ void __launch_bounds__(256)
final_atomic_kernel(const u64* __restrict__ SAB, const u64* __restrict__ dotacc,
                    const double* __restrict__ msepartA,
                    const double* __restrict__ msepartB, float* __restrict__ out)
{
  __shared__ double wpartd[4], wpartm[4];
  const int t = threadIdx.x;
  const double NMU = 4193792.0;
  double s = 0.0;
  for (int i=0;i<DCOL/256;i++){
    u64 v = SAB[i*256+t];
    s += ((double)(uint32_t)v - NMU)*((double)(uint32_t)(v>>32) - NMU);
  }
  double m = 0.0;
  for (int i=t;i<NROW;i+=256) m += msepartA[i] + msepartB[i];
  #pragma unroll
  for (int o=32;o>0;o>>=1){ s+=__shfl_down(s,o,64); m+=__shfl_down(m,o,64); }
  int lane=t&63, wid=t>>6;
  if (lane==0){ wpartd[wid]=s; wpartm[wid]=m; }
  __syncthreads();
  if (t==0){
    double sasb   = wpartd[0]+wpartd[1]+wpartd[2]+wpartd[3];
    double msesum = wpartm[0]+wpartm[1]+wpartm[2]+wpartm[3];
    const double C     = 45812983808.0;
    const double NDMU2 = 140703130714112.0;
    double dot = (double)(*dotacc);
    double diag_sum = (dot - NDMU2) / C;
    double pos = diag_sum / (double)NROW;
    double stotal = sasb / C;
    double neg = (stotal - diag_sum) / ((double)NROW*(double)(NROW-1));
    double loss1 = msesum / ((double)NROW*(double)DCOL);
    out[0] = (float)(loss1 + 1.0 - pos + neg);
  }
}

extern "C" void kernel_launch(void* const* d_in, const int* in_sizes, int n_in,
                              void* d_out, int out_size, void* d_ws, size_t ws_size,
                              hipStream_t stream)
{
  const float* pred = (const float*)d_in[0];
  const float* eeg  = (const float*)d_in[1];
  float* out = (float*)d_out;

  char* ws = (char*)d_ws;
  const size_t OFF       = (size_t)2*NROW*DCOL*sizeof(uint16_t); // 32 MB ranks
  const size_t SZ_PART   = (size_t)64*DCOL*sizeof(u64);          // 4 MB
  const size_t NEED_PART = OFF + SZ_PART + 64*sizeof(double) + 512*sizeof(u64)
                           + 2*(size_t)NROW*sizeof(double);
  const size_t NEED_ATOM = OFF + DCOL*sizeof(u64) + 8
                           + 2*(size_t)NROW*sizeof(double);

  if (ws_size >= NEED_PART){
    uint16_t* ranks  = (uint16_t*)ws;
    u64* SABpart     = (u64*)(ws + OFF);
    double* Spart    = (double*)(ws + OFF + SZ_PART);
    u64* dotpart     = (u64*)(ws + OFF + SZ_PART + 64*sizeof(double));
    double* msepartA = (double*)(ws + OFF + SZ_PART + 64*sizeof(double) + 512*sizeof(u64));
    double* msepartB = msepartA + NROW;

    rank_kernel<<<dim3(2*NROW), dim3(T1), 0, stream>>>(pred, eeg, ranks, msepartA, msepartB);
    colsum_part_kernel<<<dim3(8,64), dim3(256), 0, stream>>>(ranks, SABpart, dotpart);
    reduce2_kernel<<<dim3(64), dim3(128), 0, stream>>>(SABpart, Spart);
    final_kernel<<<dim3(1), dim3(256), 0, stream>>>(Spart, dotpart, msepartA, msepartB, out);
  } else if (ws_size >= NEED_ATOM){
    uint16_t* ranks  = (uint16_t*)ws;
    u64* SAB         = (u64*)(ws + OFF);
    u64* dotacc      = (u64*)(ws + OFF + DCOL*sizeof(u64));
    double* msepartA = (double*)(ws + OFF + DCOL*sizeof(u64) + 8);
    double* msepartB = msepartA + NROW;

    hipMemsetAsync(ws + OFF, 0, DCOL*sizeof(u64) + 8, stream);
    rank_kernel<<<dim3(2*NROW), dim3(T1), 0, stream>>>(pred, eeg, ranks, msepartA, msepartB);
    colsum_atomic_kernel<<<dim3(4,64), dim3(256), 0, stream>>>(ranks, SAB, dotacc);
    final_atomic_kernel<<<dim3(1), dim3(256), 0, stream>>>(SAB, dotacc, msepartA, msepartB, out);
  } else {
    hipMemsetAsync(d_out, 0xFF, sizeof(float), stream);  // ws too small signal
  }
}

// Round 17
// 69.580 us; speedup vs baseline: 1.0489x; 1.0489x over previous
//
#include <hip/hip_runtime.h>
#include <stdint.h>

#define NROW 1024
#define DCOL 8192
#define T1   1024
#define EPT  8
#define TSZ  1024    // CDF table entries (top 10 bits of sortable key)
#define NBIN 16384   // logical bins (u16-packed, 2 per u32 word)
#define NHW  8193    // histogram words (8192 + sentinel)

typedef unsigned long long u64;

// ---------- compile-time monotone N(0,1)-CDF binning table (scale 16384) ----
struct CdfTbl { uint32_t e[TSZ]; };

constexpr double cpow2(int p){
  double r = 1.0;
  if (p >= 0){ for (int i=0;i<p;i++) r *= 2.0; }
  else       { for (int i=0;i<-p;i++) r *= 0.5; }
  return r;
}
constexpr double key_to_x(uint32_t k){
  uint32_t u = (k & 0x80000000u) ? (k ^ 0x80000000u) : ~k;
  double sign = (u >> 31) ? -1.0 : 1.0;
  int E = (int)((u >> 23) & 255u);
  double M = (double)(u & 0x7FFFFFu);
  double mag = 0.0;
  if (E == 255)      mag = 1.0e10;              // inf/NaN band -> clamped below
  else if (E == 0)   mag = M * cpow2(-149);
  else               mag = (1.0 + M / 8388608.0) * cpow2(E - 127);
  return sign * mag;
}
constexpr double cerf(double z){                 // series, |z| <= ~3 (clamped)
  double term = z, sum = z;
  for (int n=1; n<60; ++n){
    term *= -z*z / (double)n;
    sum  += term / (double)(2*n+1);
  }
  return sum * 1.1283791670955126;               // 2/sqrt(pi)
}
constexpr double cphi(double x){
  if (x >  4.0) return 1.0;
  if (x < -4.0) return 0.0;
  return 0.5 + 0.5 * cerf(x * 0.7071067811865476);
}
constexpr CdfTbl make_tbl(){
  CdfTbl T{};
  uint32_t b[TSZ+1] = {};
  uint32_t prev = 0;
  for (int t=0; t<=TSZ; ++t){
    uint32_t bt;
    if (t == TSZ) bt = (uint32_t)NBIN;
    else {
      double c = cphi(key_to_x((uint32_t)t << 22));
      long v = (long)(c * (double)NBIN);
      if (v < 0) v = 0;
      if (v > NBIN-1) v = NBIN-1;
      bt = (uint32_t)v;
    }
    if (bt < prev) bt = prev;                    // enforce monotone
    prev = bt;
    b[t] = bt;
  }
  for (int t=0; t<TSZ; ++t) T.e[t] = (b[t] << 16) | (b[t+1] - b[t]);
  return T;
}
__device__ const CdfTbl d_cdf = make_tbl();

// order-preserving float -> uint32 transform
__device__ __forceinline__ uint32_t sortable_key(float f){
  uint32_t u = __float_as_uint(f);
  return u ^ ((uint32_t)((int32_t)u >> 31) | 0x80000000u);
}

// ---------- DPP cross-lane scans (zero-LDS) ----------
__device__ __forceinline__ uint32_t wave_scan_add(uint32_t v){
  int x = (int)v, tmp;
  tmp = __builtin_amdgcn_update_dpp(0, x, 0x111, 0xf, 0xf, false); x += tmp;
  tmp = __builtin_amdgcn_update_dpp(0, x, 0x112, 0xf, 0xf, false); x += tmp;
  tmp = __builtin_amdgcn_update_dpp(0, x, 0x114, 0xf, 0xf, false); x += tmp;
  tmp = __builtin_amdgcn_update_dpp(0, x, 0x118, 0xf, 0xf, false); x += tmp;
  tmp = __builtin_amdgcn_update_dpp(0, x, 0x142, 0xa, 0xf, false); x += tmp; // bcast15
  tmp = __builtin_amdgcn_update_dpp(0, x, 0x143, 0xc, 0xf, false); x += tmp; // bcast31
  return (uint32_t)x;
}
__device__ __forceinline__ uint32_t row16_scan_add(uint32_t v){
  int x = (int)v, tmp;
  tmp = __builtin_amdgcn_update_dpp(0, x, 0x111, 0xf, 0xf, false); x += tmp;
  tmp = __builtin_amdgcn_update_dpp(0, x, 0x112, 0xf, 0xf, false); x += tmp;
  tmp = __builtin_amdgcn_update_dpp(0, x, 0x114, 0xf, 0xf, false); x += tmp;
  tmp = __builtin_amdgcn_update_dpp(0, x, 0x118, 0xf, 0xf, false); x += tmp;
  return (uint32_t)x;
}

// One block ranks one row (session-best structure, = round-15):
// singleton buckets (cnt==1, ~61% at NBIN=16384) skip the scatter write and
// the count-loop reads -- their rank is exactly the bucket start, and their
// ek entry is never read by any other key. Multi-bucket logic unchanged.
extern "C" __global__ void __launch_bounds__(T1)
rank_kernel(const float* __restrict__ pred, const float* __restrict__ eeg,
            uint16_t* __restrict__ ranks,
            double* __restrict__ msepartA, double* __restrict__ msepartB)
{
  __shared__ uint32_t h[NHW];       // 32.8 KB: packed counts -> packed prefixes
  __shared__ uint32_t ek[DCOL];     // 32 KB: scattered keys (multi-buckets only)
  __shared__ uint32_t Tl[TSZ];      // 4 KB: CDF table; tie list after binning
  __shared__ uint32_t wt[16];
  __shared__ uint32_t listn;
  __shared__ double   redd[16];

  const int t = threadIdx.x, bid = blockIdx.x;
  const int pair = ((bid >> 4) << 3) | (bid & 7);   // [0,1024), twice each
  const bool is_eeg = (bid >> 3) & 1;
  const int lane = t & 63, wid = t >> 6;
  const float* src = is_eeg ? (eeg  + (size_t)pair * DCOL)
                            : (pred + (size_t)pair * DCOL);

  const float4* s4 = (const float4*)(src + t * EPT);
  float4 va = s4[0], vb = s4[1];

  // zero hist words (b128), load table slice, sentinel, tie counter
  {
    uint4 z = make_uint4(0u,0u,0u,0u);
    *(uint4*)&h[t*EPT]   = z;
    *(uint4*)&h[t*EPT+4] = z;
  }
  Tl[t] = d_cdf.e[t];
  if (t == 0){ listn = 0u; h[NHW-1] = (uint32_t)DCOL; } // pf16[16384] = 8192

  // balanced MSE: this block's half of the columns, against counterpart row
  double msum = 0.0;
  {
    const bool mse_act = is_eeg ? (t >= T1/2) : (t < T1/2);
    if (mse_act){
      const float* other = is_eeg ? (pred + (size_t)pair * DCOL)
                                  : (eeg  + (size_t)pair * DCOL);
      const float4* o4 = (const float4*)(other + t * EPT);
      float4 qa = o4[0], qb = o4[1];
      float d;
      d=qa.x-va.x; msum += (double)(d*d);
      d=qa.y-va.y; msum += (double)(d*d);
      d=qa.z-va.z; msum += (double)(d*d);
      d=qa.w-va.w; msum += (double)(d*d);
      d=qb.x-vb.x; msum += (double)(d*d);
      d=qb.y-vb.y; msum += (double)(d*d);
      d=qb.z-vb.z; msum += (double)(d*d);
      d=qb.w-vb.w; msum += (double)(d*d);
    }
  }

  uint32_t key[EPT];
  key[0]=sortable_key(va.x); key[1]=sortable_key(va.y);
  key[2]=sortable_key(va.z); key[3]=sortable_key(va.w);
  key[4]=sortable_key(vb.x); key[5]=sortable_key(vb.y);
  key[6]=sortable_key(vb.z); key[7]=sortable_key(vb.w);
  __syncthreads();                               // (1) zeros + table visible

  // ---- bin via table + packed histogram; atomic return = arrival order ----
  uint32_t bin[EPT], ord[EPT];
  #pragma unroll
  for (int j=0;j<EPT;j++){
    uint32_t tv = Tl[key[j] >> 22];
    bin[j] = (tv >> 16) + __umulhi(key[j] << 10, tv & 0xFFFFu);
  }
  #pragma unroll
  for (int j=0;j<EPT;j++){
    uint32_t sh = (bin[j] & 1u) << 4;
    uint32_t old = atomicAdd(&h[bin[j] >> 1], 1u << sh);
    ord[j] = (old >> sh) & 0xFFFFu;              // counts <= 8192: no carry
  }
  __syncthreads();                               // (2)

  // ---- scan: words become packed u16 exclusive prefixes, in place ----
  {
    uint4 ca = *(const uint4*)&h[t*EPT];
    uint4 cb = *(const uint4*)&h[t*EPT+4];
    uint32_t w[8] = {ca.x,ca.y,ca.z,ca.w,cb.x,cb.y,cb.z,cb.w};
    uint32_t tot = 0;
    #pragma unroll
    for (int k=0;k<8;k++) tot += (w[k] & 0xFFFFu) + (w[k] >> 16);
    uint32_t v = wave_scan_add(tot);             // inclusive, DPP (no LDS)
    if (lane==63) wt[wid]=v;
    __syncthreads();                             // (3)
    uint32_t y = wt[lane & 15];
    uint32_t pre = row16_scan_add(y);
    uint32_t off = wid ? (uint32_t)__builtin_amdgcn_readlane((int)pre, wid-1) : 0u;
    uint32_t run = off + v - tot;
    uint32_t o[8];
    #pragma unroll
    for (int k=0;k<8;k++){
      uint32_t p0 = run; run += (w[k] & 0xFFFFu);
      uint32_t p1 = run; run += (w[k] >> 16);
      o[k] = p0 | (p1 << 16);
    }
    *(uint4*)&h[t*EPT]   = make_uint4(o[0],o[1],o[2],o[3]);
    *(uint4*)&h[t*EPT+4] = make_uint4(o[4],o[5],o[6],o[7]);
  }
  __syncthreads();                               // (4)

  // ---- scatter (no atomics), MULTI-buckets only: singleton entries are
  //      never read by anyone (bucket members only scan their own bucket) ----
  const uint16_t* pf = (const uint16_t*)h;
  uint32_t stj[EPT], cntj[EPT];
  #pragma unroll
  for (int j=0;j<EPT;j++){
    uint32_t st = pf[bin[j]];
    uint32_t en = pf[bin[j] + 1];                // sentinel covers bin 16383
    stj[j]  = st;
    cntj[j] = en - st;
    if (cntj[j] > 1u) ek[st + ord[j]] = key[j];
  }
  __syncthreads();                               // (5) scatter complete

  // ---- exact rank: ILP-grouped count, singleton lanes predicated off ----
  uint32_t rk[EPT];
  uint32_t tiedmask = 0u;
  #pragma unroll
  for (int grp=0; grp<2; ++grp){
    uint32_t less[4] = {0,0,0,0}, eqc[4] = {0,0,0,0};
    uint32_t mx = 0;
    #pragma unroll
    for (int q=0;q<4;q++){
      uint32_t c = cntj[grp*4+q];
      mx = max(mx, (c > 1u) ? c : 0u);           // all-singleton group: skip
    }
    for (uint32_t p=0; p<mx; ++p){
      uint32_t k2[4];
      #pragma unroll
      for (int q=0;q<4;q++){                     // reads only for multi lanes
        int j = grp*4+q;
        if (cntj[j] > 1u) k2[q] = ek[stj[j] + min(p, cntj[j]-1u)];
        else              k2[q] = 0u;
      }
      #pragma unroll
      for (int q=0;q<4;q++){
        int j = grp*4+q;
        if (cntj[j] > 1u && p < cntj[j]){
          less[q] += (k2[q] <  key[j]) ? 1u : 0u;
          eqc[q]  += (k2[q] == key[j]) ? 1u : 0u;
        }
      }
    }
    #pragma unroll
    for (int q=0;q<4;q++){
      int j = grp*4+q;
      rk[j] = stj[j] + less[q];                  // singleton: less=0 -> rank=st
      if (eqc[q] > 1u){                          // rare: true float dup
        uint32_t pp = atomicAdd(&listn, 1u);
        if (pp < TSZ/2){ Tl[2*pp] = key[j]; Tl[2*pp+1] = (uint32_t)(t*EPT+j); }
        tiedmask |= (1u << j);
      }
    }
  }
  __syncthreads();                               // (6) tie list complete
  if (tiedmask){
    uint32_t n = min(listn, (uint32_t)(TSZ/2));
    #pragma unroll
    for (int j=0;j<EPT;j++){
      if (tiedmask & (1u<<j)){
        uint32_t add = 0, me = (uint32_t)(t*EPT+j);
        for (uint32_t q=0;q<n;q++)
          add += (Tl[2*q] == key[j] && Tl[2*q+1] < me) ? 1u : 0u;
        rk[j] += add;
      }
    }
  }

  uint4 pk;
  pk.x = rk[0] | (rk[1]<<16);
  pk.y = rk[2] | (rk[3]<<16);
  pk.z = rk[4] | (rk[5]<<16);
  pk.w = rk[6] | (rk[7]<<16);
  const size_t orow = is_eeg ? (size_t)(NROW + pair) : (size_t)pair;
  *(uint4*)(ranks + orow*DCOL + (size_t)t*EPT) = pk;

  // block-wide MSE-half reduction (inactive threads contribute 0)
  #pragma unroll
  for (int o=32;o>0;o>>=1) msum += __shfl_down(msum,o,64);
  if (lane==0) redd[wid]=msum;
  __syncthreads();
  if (t==0){
    double m=0.0;
    #pragma unroll
    for (int w=0;w<16;w++) m += redd[w];
    (is_eeg ? msepartB : msepartA)[pair] = m;
  }
}

// ---------- atomic-free back end (256 thr: 8 waves/CU for latency hiding) ---
extern "C" __global__ void __launch_bounds__(256)
colsum_part_kernel(const uint16_t* __restrict__ ranks,
                   u64* __restrict__ SABpart, u64* __restrict__ dotpart)
{
  __shared__ u64 redu[4];
  const int t = threadIdx.x;
  const int bx = blockIdx.x, by = blockIdx.y;
  const int col = bx*1024 + t*4;
  const int r0  = by*16;
  const uint16_t* rp = ranks;
  const uint16_t* re = ranks + (size_t)NROW*DCOL;
  uint32_t sa[4] = {0,0,0,0};
  uint32_t sb[4] = {0,0,0,0};
  u64 dt = 0ull;
  #pragma unroll
  for (int i=0;i<16;i++){
    uint2 a = *(const uint2*)&rp[(size_t)(r0+i)*DCOL + col];
    uint2 b = *(const uint2*)&re[(size_t)(r0+i)*DCOL + col];
    uint32_t aw[4] = {a.x&0xFFFFu,a.x>>16,a.y&0xFFFFu,a.y>>16};
    uint32_t bw[4] = {b.x&0xFFFFu,b.x>>16,b.y&0xFFFFu,b.y>>16};
    uint32_t rowdt = 0;
    #pragma unroll
    for (int k=0;k<4;k++){ sa[k]+=aw[k]; sb[k]+=bw[k]; rowdt += aw[k]*bw[k]; }
    dt += (u64)rowdt;                            // rowdt <= 4*8191^2 < 2^32
  }
  u64* dst = SABpart + (size_t)by*DCOL + col;
  #pragma unroll
  for (int k=0;k<4;k++) dst[k] = (u64)sa[k] | ((u64)sb[k]<<32);

  #pragma unroll
  for (int o=32;o>0;o>>=1) dt += __shfl_down(dt,o,64);
  int lane=t&63, wid=t>>6;
  if (lane==0) redu[wid]=dt;
  __syncthreads();
  if (t==0) dotpart[by*8+bx] = redu[0]+redu[1]+redu[2]+redu[3];
}

extern "C" __global__ void __launch_bounds__(128)
reduce2_kernel(const u64* __restrict__ SABpart, double* __restrict__ Spart)
{
  __shared__ double red[2];
  const int t = threadIdx.x;
  const int col = blockIdx.x*128 + t;
  u64 s = 0ull;
  #pragma unroll
  for (int by=0; by<64; by++) s += SABpart[(size_t)by*DCOL + col];
  const double NMU = 4193792.0;                  // N * mu, mu = (D-1)/2
  double d = ((double)(uint32_t)s - NMU) * ((double)(uint32_t)(s>>32) - NMU);
  #pragma unroll
  for (int o=32;o>0;o>>=1) d += __shfl_down(d,o,64);
  int lane=t&63, wid=t>>6;
  if (lane==0) red[wid]=d;
  __syncthreads();
  if (t==0) Spart[blockIdx.x] = red[0]+red[1];
}

extern "C" __global__ void __launch_bounds__(256)
final_kernel(const double* __restrict__ Spart, const u64* __restrict__ dotpart,
             const double* __restrict__ msepartA,
             const double* __restrict__ msepartB, float* __restrict__ out)
{
  __shared__ double wpartd[4], wpartm[4];
  __shared__ u64 wpartu[4];
  const int t = threadIdx.x;
  double s = (t < 64) ? Spart[t] : 0.0;
  u64 d = dotpart[t] + dotpart[t+256];
  double m = 0.0;
  for (int i=t;i<NROW;i+=256) m += msepartA[i] + msepartB[i];
  #pragma unroll
  for (int o=32;o>0;o>>=1){
    s+=__shfl_down(s,o,64); m+=__shfl_down(m,o,64); d+=__shfl_down(d,o,64);
  }
  int lane=t&63, wid=t>>6;
  if (lane==0){ wpartd[wid]=s; wpartm[wid]=m; wpartu[wid]=d; }
  __syncthreads();
  if (t==0){
    double sasb   = wpartd[0]+wpartd[1]+wpartd[2]+wpartd[3];
    double msesum = wpartm[0]+wpartm[1]+wpartm[2]+wpartm[3];
    double dot    = (double)(wpartu[0]+wpartu[1]+wpartu[2]+wpartu[3]);
    const double C     = 45812983808.0;          // D*(D^2-1)/12
    const double NDMU2 = 140703130714112.0;      // N * D * mu^2
    double diag_sum = (dot - NDMU2) / C;         // sum_i corr_ii
    double pos = diag_sum / (double)NROW;
    double stotal = sasb / C;                    // sum_ij corr_ij
    double neg = (stotal - diag_sum) / ((double)NROW*(double)(NROW-1));
    double loss1 = msesum / ((double)NROW*(double)DCOL);
    out[0] = (float)(loss1 + 1.0 - pos + neg);
  }
}

// ---------- atomic fallback (only if ws too small for partials) ----------
extern "C" __global__ void __launch_bounds__(256)
colsum_atomic_kernel(const uint16_t* __restrict__ ranks,
                     u64* __restrict__ SAB, u64* __restrict__ dotacc)
{
  const int t = threadIdx.x;
  const int col = blockIdx.x*2048 + t*8;
  const int r0  = blockIdx.y*16;
  const uint16_t* rp = ranks;
  const uint16_t* re = ranks + (size_t)NROW*DCOL;
  uint32_t sa[8] = {0,0,0,0,0,0,0,0};
  uint32_t sb[8] = {0,0,0,0,0,0,0,0};
  u64 dt = 0ull;
  for (int i=0;i<16;i++){
    uint4 a = *(const uint4*)&rp[(size_t)(r0+i)*DCOL + col];
    uint4 b = *(const uint4*)&re[(size_t)(r0+i)*DCOL + col];
    uint32_t aw[8] = {a.x&0xFFFFu,a.x>>16,a.y&0xFFFFu,a.y>>16,
                      a.z&0xFFFFu,a.z>>16,a.w&0xFFFFu,a.w>>16};
    uint32_t bw[8] = {b.x&0xFFFFu,b.x>>16,b.y&0xFFFFu,b.y>>16,
                      b.z&0xFFFFu,b.z>>16,b.w&0xFFFFu,b.w>>16};
    uint32_t rowdt = 0;
    #pragma unroll
    for (int k=0;k<8;k++){ sa[k]+=aw[k]; sb[k]+=bw[k]; rowdt += aw[k]*bw[k]; }
    dt += (u64)rowdt;
  }
  #pragma unroll
  for (int k=0;k<8;k++)
    atomicAdd(&SAB[col+k], (u64)sa[k] | ((u64)sb[k]<<32));
  #pragma unroll
  for (int o=32;o>0;o>>=1) dt += __shfl_down(dt,o,64);
  if ((t&63)==0) atomicAdd(dotacc, dt);
}

extern "C" __global__ void __launch_bounds__(256)
final_atomic_kernel(const u64* __restrict__ SAB, const u64* __restrict__ dotacc,
                    const double* __restrict__ msepartA,
                    const double* __restrict__ msepartB, float* __restrict__ out)
{
  __shared__ double wpartd[4], wpartm[4];
  const int t = threadIdx.x;
  const double NMU = 4193792.0;
  double s = 0.0;
  for (int i=0;i<DCOL/256;i++){
    u64 v = SAB[i*256+t];
    s += ((double)(uint32_t)v - NMU)*((double)(uint32_t)(v>>32) - NMU);
  }
  double m = 0.0;
  for (int i=t;i<NROW;i+=256) m += msepartA[i] + msepartB[i];
  #pragma unroll
  for (int o=32;o>0;o>>=1){ s+=__shfl_down(s,o,64); m+=__shfl_down(m,o,64); }
  int lane=t&63, wid=t>>6;
  if (lane==0){ wpartd[wid]=s; wpartm[wid]=m; }
  __syncthreads();
  if (t==0){
    double sasb   = wpartd[0]+wpartd[1]+wpartd[2]+wpartd[3];
    double msesum = wpartm[0]+wpartm[1]+wpartm[2]+wpartm[3];
    const double C     = 45812983808.0;
    const double NDMU2 = 140703130714112.0;
    double dot = (double)(*dotacc);
    double diag_sum = (dot - NDMU2) / C;
    double pos = diag_sum / (double)NROW;
    double stotal = sasb / C;
    double neg = (stotal - diag_sum) / ((double)NROW*(double)(NROW-1));
    double loss1 = msesum / ((double)NROW*(double)DCOL);
    out[0] = (float)(loss1 + 1.0 - pos + neg);
  }
}

extern "C" void kernel_launch(void* const* d_in, const int* in_sizes, int n_in,
                              void* d_out, int out_size, void* d_ws, size_t ws_size,
                              hipStream_t stream)
{
  const float* pred = (const float*)d_in[0];
  const float* eeg  = (const float*)d_in[1];
  float* out = (float*)d_out;

  char* ws = (char*)d_ws;
  const size_t OFF       = (size_t)2*NROW*DCOL*sizeof(uint16_t); // 32 MB ranks
  const size_t SZ_PART   = (size_t)64*DCOL*sizeof(u64);          // 4 MB
  const size_t NEED_PART = OFF + SZ_PART + 64*sizeof(double) + 512*sizeof(u64)
                           + 2*(size_t)NROW*sizeof(double);
  const size_t NEED_ATOM = OFF + DCOL*sizeof(u64) + 8
                           + 2*(size_t)NROW*sizeof(double);

  if (ws_size >= NEED_PART){
    uint16_t* ranks  = (uint16_t*)ws;
    u64* SABpart     = (u64*)(ws + OFF);
    double* Spart    = (double*)(ws + OFF + SZ_PART);
    u64* dotpart     = (u64*)(ws + OFF + SZ_PART + 64*sizeof(double));
    double* msepartA = (double*)(ws + OFF + SZ_PART + 64*sizeof(double) + 512*sizeof(u64));
    double* msepartB = msepartA + NROW;

    rank_kernel<<<dim3(2*NROW), dim3(T1), 0, stream>>>(pred, eeg, ranks, msepartA, msepartB);
    colsum_part_kernel<<<dim3(8,64), dim3(256), 0, stream>>>(ranks, SABpart, dotpart);
    reduce2_kernel<<<dim3(64), dim3(128), 0, stream>>>(SABpart, Spart);
    final_kernel<<<dim3(1), dim3(256), 0, stream>>>(Spart, dotpart, msepartA, msepartB, out);
  } else if (ws_size >= NEED_ATOM){
    uint16_t* ranks  = (uint16_t*)ws;
    u64* SAB         = (u64*)(ws + OFF);
    u64* dotacc      = (u64*)(ws + OFF + DCOL*sizeof(u64));
    double* msepartA = (double*)(ws + OFF + DCOL*sizeof(u64) + 8);
    double* msepartB = msepartA + NROW;

    hipMemsetAsync(ws + OFF, 0, DCOL*sizeof(u64) + 8, stream);
    rank_kernel<<<dim3(2*NROW), dim3(T1), 0, stream>>>(pred, eeg, ranks, msepartA, msepartB);
    colsum_atomic_kernel<<<dim3(4,64), dim3(256), 0, stream>>>(ranks, SAB, dotacc);
    final_atomic_kernel<<<dim3(1), dim3(256), 0, stream>>>(SAB, dotacc, msepartA, msepartB, out);
  } else {
    hipMemsetAsync(d_out, 0xFF, sizeof(float), stream);  // ws too small signal
  }
}